// Round 7
// baseline (1312.548 us; speedup 1.0000x reference)
//
#include <hip/hip_runtime.h>
#include <stdint.h>

// LTC encoder B=256,T=1024,F=64,H=128. One WG per batch row.
// R15 = R14 resubmitted (prior bench died on container infra, not kernel:
// barrier parity, OOB, and ring-race audits all clean).
// R14 = R13 single-barrier structure reshaped to 32x32x16 MFMA, 8 waves.
// R13 post-mortem: VALU 63 + MFMA 27 ~= 90% -> issue-bound; tail VALU and
// LDS fragment reads are per-WAVE costs, so serving 32 cols/wave via
// mfma_f32_32x32x16_f16 (waves 0-3 = layer0, 4-7 = layer1, NT=512) halves
// total issue per CU. Broadcast-A still: each 32-lane half reads one 16B
// LDS address (k-window (l>>5)*8, the 32x32 analog of the verified 16x16
// mapping); C/D col=lane&31 (HW-verified m74/m101). 2 waves/SIMD -> 256-reg
// unified budget: group-B 24 weight frags (96 VGPR) + 3x f32x16 acc fit,
// spill dead. Same LN-distributed math as R12/R13 (verified): ONE
// __syncthreads per step, stats via LDS atomicAdd 4-ring, mu/rstd derived
// by consumers next phase, gamma folded into weight k-dim.

#define B_ 256
#define T_ 1024
#define F_ 64
#define H_ 128
#define EPS_ 1e-5f
#define NT_ 512

typedef _Float16 h2 __attribute__((ext_vector_type(2)));
typedef _Float16 h8 __attribute__((ext_vector_type(8)));
typedef float f32x16 __attribute__((ext_vector_type(16)));
typedef __fp16  f16v2 __attribute__((ext_vector_type(2)));

__device__ __forceinline__ h2 pkf16(float a, float b) {
  union { f16v2 f; h2 h; } c;
  c.f = __builtin_amdgcn_cvt_pkrtz(a, b);
  return c.h;
}
__device__ __forceinline__ uint32_t as_u32(h2 h) { union { h2 h; uint32_t u; } c; c.h = h; return c.u; }

#if __has_builtin(__builtin_amdgcn_rsqf)
__device__ __forceinline__ float rsq_fast(float x) { return __builtin_amdgcn_rsqf(x); }
#else
__device__ __forceinline__ float rsq_fast(float x) { return rsqrtf(x); }
#endif

// 16-lane sum via DPP row_ror (every lane of each 16-row gets the row sum).
#if __has_builtin(__builtin_amdgcn_update_dpp)
template <int CTRL>
__device__ __forceinline__ float dpp_add(float v) {
  union { float f; int i; } a, b;
  a.f = v;
  b.i = __builtin_amdgcn_update_dpp(0, a.i, CTRL, 0xf, 0xf, true);
  return v + b.f;
}
__device__ __forceinline__ float red16(float v) {
  v = dpp_add<0x128>(v);   // row_ror:8
  v = dpp_add<0x124>(v);   // row_ror:4
  v = dpp_add<0x122>(v);   // row_ror:2
  v = dpp_add<0x121>(v);   // row_ror:1
  return v;
}
#else
__device__ __forceinline__ float red16(float v) {
  v += __shfl_xor(v, 1); v += __shfl_xor(v, 2);
  v += __shfl_xor(v, 4); v += __shfl_xor(v, 8);
  return v;
}
#endif

// pack 8 consecutive fp32 weights into one MFMA half-fragment (4 VGPRs)
__device__ __forceinline__ h8 packfrag(const float* p) {
  float4 a = *(const float4*)p;
  float4 b = *(const float4*)(p + 4);
  union { h2 h[4]; h8 v; } c;
  c.h[0] = pkf16(a.x, a.y); c.h[1] = pkf16(a.z, a.w);
  c.h[2] = pkf16(b.x, b.y); c.h[3] = pkf16(b.z, b.w);
  return c.v;
}
// load 8 fp32 weights, fold LN-gamma into the k-dim, accumulate Sum(w*g)
// (= sum of folded values) and Sum(w*be); return folded frag as f16.
__device__ __forceinline__ h8 packfrag_g(const float* w, const float* gv, const float* bv,
                                         float& dg, float& dbe) {
  float4 a = *(const float4*)w;
  float4 b = *(const float4*)(w + 4);
  float4 ga = *(const float4*)gv;
  float4 gb = *(const float4*)(gv + 4);
  float4 ba = *(const float4*)bv;
  float4 bb = *(const float4*)(bv + 4);
  float w0 = a.x*ga.x, w1 = a.y*ga.y, w2 = a.z*ga.z, w3 = a.w*ga.w;
  float w4 = b.x*gb.x, w5 = b.y*gb.y, w6 = b.z*gb.z, w7 = b.w*gb.w;
  dg  += (w0 + w1) + (w2 + w3) + (w4 + w5) + (w6 + w7);
  dbe += a.x*ba.x + a.y*ba.y + a.z*ba.z + a.w*ba.w
       + b.x*bb.x + b.y*bb.y + b.z*bb.z + b.w*bb.w;
  union { h2 h[4]; h8 v; } c;
  c.h[0] = pkf16(w0, w1); c.h[1] = pkf16(w2, w3);
  c.h[2] = pkf16(w4, w5); c.h[3] = pkf16(w6, w7);
  return c.v;
}
// broadcast A-fragment from packed-f16 LDS (16B per 32-lane half, conflict-free)
__device__ __forceinline__ h8 ldfrag(const uint32_t* p) {
  union { uint4 u; h8 v; } c;
  c.u = *(const uint4*)p;
  return c.v;
}

__device__ __forceinline__ float tanh_fast(float a) {
  float aa = fabsf(a);
  float e  = __expf(2.f * aa);
  float th = 1.f - 2.f * __builtin_amdgcn_rcpf(e + 1.f);
  return copysignf(th, a);
}
__device__ __forceinline__ float softplus_fast(float x) {
  return (x > 20.f) ? x : __logf(1.f + __expf(x));
}

#define MFMA32(A_, B_, C_) __builtin_amdgcn_mfma_f32_32x32x16_f16(A_, B_, C_, 0, 0, 0)

__global__ void __attribute__((amdgpu_flat_work_group_size(NT_, NT_)))
                __attribute__((amdgpu_waves_per_eu(2, 2)))
ltc_scan(
    const float* __restrict__ x,
    const float* __restrict__ Wh0, const float* __restrict__ bh0,
    const float* __restrict__ Wx0, const float* __restrict__ bx0,
    const float* __restrict__ Wt0, const float* __restrict__ bt0,
    const float* __restrict__ tau0, const float* __restrict__ g0,
    const float* __restrict__ be0,
    const float* __restrict__ Wh1, const float* __restrict__ bh1,
    const float* __restrict__ Wx1, const float* __restrict__ bx1,
    const float* __restrict__ Wt1, const float* __restrict__ bt1,
    const float* __restrict__ tau1, const float* __restrict__ g1,
    const float* __restrict__ be1,
    float* __restrict__ out)
{
  __shared__ __align__(16) uint32_t h0p[2][64];   // hc0 packed f16, dbuf
  __shared__ __align__(16) uint32_t h1p[2][64];   // hc1 packed f16, dbuf
  __shared__ __align__(16) uint32_t x4[4][32];    // x[t] packed f16, 4-ring
  __shared__ __align__(16) float    part[4][4];   // {s_L0,s2_L0,s_L1,s2_L1} 4-ring

  const int tid = threadIdx.x;
  const int wid = tid >> 6;
  const int l   = tid & 63;
  const int hh  = l >> 5;           // k-half (0/1)
  const int g4b = hh << 2;          // LDS u32 offset of this half's frag
  const int kb  = hh << 3;          // k offset (floats) of this half
  const int cl  = l & 31;           // column within wave tile
  const int b   = blockIdx.x;
  const float* xg = x + (size_t)b * (T_ * F_);

  if (tid < 128) { ((uint32_t*)h0p)[tid] = 0u; ((uint32_t*)h1p)[tid] = 0u; }
  if (tid < 16)  ((float*)part)[tid] = 0.f;
  if (tid < 32) {                   // stage x[0], x[1]
    float2 a = *(const float2*)(xg + 2 * tid);
    float2 c = *(const float2*)(xg + F_ + 2 * tid);
    x4[0][tid] = as_u32(pkf16(a.x, a.y));
    x4[1][tid] = as_u32(pkf16(c.x, c.y));
  }
  __syncthreads();

  if (wid < 4) {
    // ================= group A: layer 0, step t = i =================
    const int c = wid * 32 + cl;
    h8 wh[8], wx[4], wt[4];
    float cg, cb;                    // (Wh0.g0)[c], (Wh0.be0)[c]
    {
      float dg = 0.f, db = 0.f;
      const float* p = Wh0 + c * H_ + kb;
      #pragma unroll
      for (int m = 0; m < 8; ++m)
        wh[m] = packfrag_g(p + 16 * m, g0 + kb + 16 * m, be0 + kb + 16 * m, dg, db);
      dg += __shfl_xor(dg, 32);      // other k-half (cols distinct per lane)
      db += __shfl_xor(db, 32);
      cg = dg; cb = db;
      const float* q = Wx0 + c * F_ + kb;
      const float* r = Wt0 + c * F_ + kb;
      #pragma unroll
      for (int m = 0; m < 4; ++m) { wx[m] = packfrag(q + 16 * m); wt[m] = packfrag(r + 16 * m); }
    }
    const float bhx = bh0[c] + bx0[c];
    const float btr = bt0[c], taub = tau0[c], gr = g0[c], ber = be0[c];
    const int  widx = wid * 16 + (cl >> 1);
    const bool wlane = ((l & 33) == 0);            // lower half, even col
    const bool st = (wid == 0) && (l < 32);

    float hcp = 0.f;
    float2 xcur;                     // x[i+2], loaded one phase early
    if (st) xcur = *(const float2*)(xg + 2 * F_ + 2 * l);

    #pragma unroll 4
    for (int i = 0; i <= T_; ++i) {
      const float2 stt = *(const float2*)&part[(i + 3) & 3][0];  // L0 stats of hc0[i-1]
      if (st) {                      // write x[i+2]; issue load of x[i+3]
        x4[(i + 2) & 3][l] = as_u32(pkf16(xcur.x, xcur.y));
        int tn = (i + 3 < T_) ? (i + 3) : (T_ - 1);
        xcur = *(const float2*)(xg + tn * F_ + 2 * l);
      }
      const uint32_t* ub = h0p[(i + 1) & 1];       // hc0[i-1]
      const uint32_t* xb = x4[i & 3];              // x[i]
      f32x16 aH = {0,0,0,0,0,0,0,0,0,0,0,0,0,0,0,0};
      f32x16 aX = {bhx,0,0,0,0,0,0,0,0,0,0,0,0,0,0,0};
      f32x16 aT = {btr,0,0,0,0,0,0,0,0,0,0,0,0,0,0,0};
      #pragma unroll
      for (int m = 0; m < 8; ++m)
        aH = MFMA32(ldfrag(ub + m * 8 + g4b), wh[m], aH);
      #pragma unroll
      for (int m = 0; m < 4; ++m) {
        h8 xf = ldfrag(xb + m * 8 + g4b);
        aX = MFMA32(xf, wx[m], aX);
        aT = MFMA32(xf, wt[m], aT);
      }
      float mu = stt.x * (1.f / 128.f);
      float m2 = stt.y * (1.f / 128.f);
      float rstd = rsq_fast(m2 - mu * mu + EPS_);
      float fl = (i > 0) ? 1.f : 0.f;
      float sc = fl * rstd;
      float pa = fmaf(sc, aH[0], fmaf(-sc * mu, cg, fl * cb)) + aX[0];
      float pt = aT[0];
      float f   = tanh_fast(pa);
      float tau = taub + softplus_fast(pt);
      float hold = fl * fmaf((hcp - mu) * rstd, gr, ber);   // hn0[i-1][c]
      float hc  = fmaf(f - hold, __builtin_amdgcn_rcpf(tau), hold);
      float hc2 = __shfl_xor(hc, 1);               // partner col (even lanes)
      if (wlane) h0p[i & 1][widx] = as_u32(pkf16(hc, hc2));
      float s  = red16(hc);  s  += __shfl_xor(s, 16);   // 32-col sum
      float s2 = red16(hc * hc); s2 += __shfl_xor(s2, 16);
      if (l == 0)  atomicAdd(&part[i & 3][0], s);  // dup upper half has s2
      if (l == 32) atomicAdd(&part[i & 3][1], s2);
      hcp = hc;
      __syncthreads();                             // the ONE barrier per phase
    }
  } else {
    // ================= group B: layer 1, step t = i-1 =================
    const int c = (wid - 4) * 32 + cl;
    h8 vh[8], vx[8], vt[8];
    float cAg, cAb, cBg, cBb, cTg, cTb;
    {
      float d1 = 0.f, d2 = 0.f, d3 = 0.f, d4 = 0.f, d5 = 0.f, d6 = 0.f;
      const float* p = Wh1 + c * H_ + kb;
      const float* q = Wx1 + c * H_ + kb;
      const float* r = Wt1 + c * H_ + kb;
      #pragma unroll
      for (int m = 0; m < 8; ++m) {
        vh[m] = packfrag_g(p + 16 * m, g1 + kb + 16 * m, be1 + kb + 16 * m, d1, d2);
        vx[m] = packfrag_g(q + 16 * m, g0 + kb + 16 * m, be0 + kb + 16 * m, d3, d4);
        vt[m] = packfrag_g(r + 16 * m, g0 + kb + 16 * m, be0 + kb + 16 * m, d5, d6);
      }
      d1 += __shfl_xor(d1, 32); d2 += __shfl_xor(d2, 32);
      d3 += __shfl_xor(d3, 32); d4 += __shfl_xor(d4, 32);
      d5 += __shfl_xor(d5, 32); d6 += __shfl_xor(d6, 32);
      cAg = d1; cAb = d2; cBg = d3; cBb = d4; cTg = d5; cTb = d6;
    }
    const float bhx = bh1[c] + bx1[c];
    const float btr = bt1[c], taub = tau1[c], gr = g1[c], ber = be1[c];
    const int  widx = (wid - 4) * 16 + (cl >> 1);
    const bool wlane = ((l & 33) == 0);
    const bool zt = (tid == NT_ - 1);              // ring zero-er

    float hcp = 0.f;
    #pragma unroll 4
    for (int i = 0; i <= T_; ++i) {
      const float4 P = *(const float4*)&part[(i + 3) & 3][0];  // both layers' stats
      if (zt) *(float4*)&part[(i + 2) & 3][0] = make_float4(0.f, 0.f, 0.f, 0.f);
      const uint32_t* u1b = h1p[(i + 1) & 1];      // hc1[i-2]
      const uint32_t* u0b = h0p[(i + 1) & 1];      // hc0[i-1]
      f32x16 aA = {0,0,0,0,0,0,0,0,0,0,0,0,0,0,0,0};
      f32x16 aB = {bhx,0,0,0,0,0,0,0,0,0,0,0,0,0,0,0};
      f32x16 aT = {btr,0,0,0,0,0,0,0,0,0,0,0,0,0,0,0};
      #pragma unroll
      for (int m = 0; m < 8; ++m)
        aA = MFMA32(ldfrag(u1b + m * 8 + g4b), vh[m], aA);
      #pragma unroll
      for (int m = 0; m < 8; ++m) {
        h8 f0 = ldfrag(u0b + m * 8 + g4b);
        aB = MFMA32(f0, vx[m], aB);
        aT = MFMA32(f0, vt[m], aT);
      }
      float mu0 = P.x * (1.f / 128.f), m20 = P.y * (1.f / 128.f);
      float mu1 = P.z * (1.f / 128.f), m21 = P.w * (1.f / 128.f);
      float rstd0 = rsq_fast(m20 - mu0 * mu0 + EPS_);
      float rstd1 = rsq_fast(m21 - mu1 * mu1 + EPS_);
      float fl0 = (i > 0) ? 1.f : 0.f;
      float fl1 = (i > 1) ? 1.f : 0.f;
      float sc0 = fl0 * rstd0, sc1 = fl1 * rstd1;
      float pa = fmaf(sc1, aA[0], fmaf(-sc1 * mu1, cAg, fl1 * cAb))
               + fmaf(sc0, aB[0], fmaf(-sc0 * mu0, cBg, fl0 * cBb));
      float pt = fmaf(sc0, aT[0], fmaf(-sc0 * mu0, cTg, fl0 * cTb));
      float f   = tanh_fast(pa);
      float tau = taub + softplus_fast(pt);
      float hold = fl1 * fmaf((hcp - mu1) * rstd1, gr, ber);  // hn1[i-2][c]
      float hc  = fmaf(f - hold, __builtin_amdgcn_rcpf(tau), hold);
      float hc2 = __shfl_xor(hc, 1);
      bool we = (i > 0);
      if (we && wlane) h1p[i & 1][widx] = as_u32(pkf16(hc, hc2));
      float s  = red16(hc);  s  += __shfl_xor(s, 16);
      float s2 = red16(hc * hc); s2 += __shfl_xor(s2, 16);
      if (we && l == 0)  atomicAdd(&part[i & 3][2], s);
      if (we && l == 32) atomicAdd(&part[i & 3][3], s2);
      if (we) hcp = hc;
      __syncthreads();                             // the ONE barrier per phase
    }
    // epilogue: hn1[T-1] from stats published at phase T_ (slot T_&3 = 0)
    {
      float mu1 = part[T_ & 3][2] * (1.f / 128.f);
      float m21 = part[T_ & 3][3] * (1.f / 128.f);
      float rstd1 = rsq_fast(m21 - mu1 * mu1 + EPS_);
      float hn = fmaf((hcp - mu1) * rstd1, gr, ber);
      if (l < 32) out[b * H_ + c] = hn;
    }
  }
}

extern "C" void kernel_launch(void* const* d_in, const int* in_sizes, int n_in,
                              void* d_out, int out_size, void* d_ws, size_t ws_size,
                              hipStream_t stream) {
  const float* x    = (const float*)d_in[0];
  const float* Wh0  = (const float*)d_in[1];
  const float* bh0  = (const float*)d_in[2];
  const float* Wx0  = (const float*)d_in[3];
  const float* bx0  = (const float*)d_in[4];
  const float* Wt0  = (const float*)d_in[5];
  const float* bt0  = (const float*)d_in[6];
  const float* tau0 = (const float*)d_in[7];
  const float* g0   = (const float*)d_in[8];
  const float* be0  = (const float*)d_in[9];
  const float* Wh1  = (const float*)d_in[10];
  const float* bh1  = (const float*)d_in[11];
  const float* Wx1  = (const float*)d_in[12];
  const float* bx1  = (const float*)d_in[13];
  const float* Wt1  = (const float*)d_in[14];
  const float* bt1  = (const float*)d_in[15];
  const float* tau1 = (const float*)d_in[16];
  const float* g1   = (const float*)d_in[17];
  const float* be1  = (const float*)d_in[18];
  float* out        = (float*)d_out;

  ltc_scan<<<B_, NT_, 0, stream>>>(x, Wh0, bh0, Wx0, bx0, Wt0, bt0, tau0, g0, be0,
                                   Wh1, bh1, Wx1, bx1, Wt1, bt1, tau1, g1, be1, out);
}

// Round 8
// 1015.116 us; speedup vs baseline: 1.2930x; 1.2930x over previous
//
#include <hip/hip_runtime.h>
#include <stdint.h>

// LTC encoder B=256,T=1024,F=64,H=128. One WG per batch row.
// R16: 8 waves x 32 cols/wave, but with 16x16x32 MFMA (two 16-col tiles).
// R15 post-mortem: 32x32x16 passed correctness but costs ~32 SIMD-cyc/instr
// (vs ~19 for 16x16x32) -> MfmaUtil 44% and regression, plus f32x16 accs
// spilled at the ~128 arch-VGPR cap (WRITE 52MB). Fix: keep the per-wave
// VALU halving (8 waves, 32 cols each) but compute each wave's cols as TWO
// 16x16x32 tiles: A-frags (h) shared by both tiles (same 6-8 ds_reads);
// tile merge in tail is ONE cndmask (tile1 acc[0] at lanes 16-31 already
// holds cols 16-31: C/D col=lane&15 + dup groups); accs are f32x4 (24 regs)
// not f32x16. Single red16 for stats: dup lanes 32-63 carry hc^2.
// Group B unroll 2 (reg pressure), group A unroll 4.
// Same verified LN-distributed single-barrier math as R12/R13/R15.

#define B_ 256
#define T_ 1024
#define F_ 64
#define H_ 128
#define EPS_ 1e-5f
#define NT_ 512

typedef _Float16 h2 __attribute__((ext_vector_type(2)));
typedef _Float16 h8 __attribute__((ext_vector_type(8)));
typedef float f32x4 __attribute__((ext_vector_type(4)));
typedef __fp16  f16v2 __attribute__((ext_vector_type(2)));

__device__ __forceinline__ h2 pkf16(float a, float b) {
  union { f16v2 f; h2 h; } c;
  c.f = __builtin_amdgcn_cvt_pkrtz(a, b);
  return c.h;
}
__device__ __forceinline__ uint32_t as_u32(h2 h) { union { h2 h; uint32_t u; } c; c.h = h; return c.u; }

#if __has_builtin(__builtin_amdgcn_rsqf)
__device__ __forceinline__ float rsq_fast(float x) { return __builtin_amdgcn_rsqf(x); }
#else
__device__ __forceinline__ float rsq_fast(float x) { return rsqrtf(x); }
#endif

// 16-lane sum via DPP row_ror (every lane of each 16-row gets the row sum).
#if __has_builtin(__builtin_amdgcn_update_dpp)
template <int CTRL>
__device__ __forceinline__ float dpp_add(float v) {
  union { float f; int i; } a, b;
  a.f = v;
  b.i = __builtin_amdgcn_update_dpp(0, a.i, CTRL, 0xf, 0xf, true);
  return v + b.f;
}
__device__ __forceinline__ float red16(float v) {
  v = dpp_add<0x128>(v);   // row_ror:8
  v = dpp_add<0x124>(v);   // row_ror:4
  v = dpp_add<0x122>(v);   // row_ror:2
  v = dpp_add<0x121>(v);   // row_ror:1
  return v;
}
#else
__device__ __forceinline__ float red16(float v) {
  v += __shfl_xor(v, 1); v += __shfl_xor(v, 2);
  v += __shfl_xor(v, 4); v += __shfl_xor(v, 8);
  return v;
}
#endif

// pack 8 consecutive fp32 weights into one MFMA half-fragment (4 VGPRs)
__device__ __forceinline__ h8 packfrag(const float* p) {
  float4 a = *(const float4*)p;
  float4 b = *(const float4*)(p + 4);
  union { h2 h[4]; h8 v; } c;
  c.h[0] = pkf16(a.x, a.y); c.h[1] = pkf16(a.z, a.w);
  c.h[2] = pkf16(b.x, b.y); c.h[3] = pkf16(b.z, b.w);
  return c.v;
}
// load 8 fp32 weights, fold LN-gamma into the k-dim, accumulate Sum(w*g)
// (= sum of folded values) and Sum(w*be); return folded frag as f16.
__device__ __forceinline__ h8 packfrag_g(const float* w, const float* gv, const float* bv,
                                         float& dg, float& dbe) {
  float4 a = *(const float4*)w;
  float4 b = *(const float4*)(w + 4);
  float4 ga = *(const float4*)gv;
  float4 gb = *(const float4*)(gv + 4);
  float4 ba = *(const float4*)bv;
  float4 bb = *(const float4*)(bv + 4);
  float w0 = a.x*ga.x, w1 = a.y*ga.y, w2 = a.z*ga.z, w3 = a.w*ga.w;
  float w4 = b.x*gb.x, w5 = b.y*gb.y, w6 = b.z*gb.z, w7 = b.w*gb.w;
  dg  += (w0 + w1) + (w2 + w3) + (w4 + w5) + (w6 + w7);
  dbe += a.x*ba.x + a.y*ba.y + a.z*ba.z + a.w*ba.w
       + b.x*bb.x + b.y*bb.y + b.z*bb.z + b.w*bb.w;
  union { h2 h[4]; h8 v; } c;
  c.h[0] = pkf16(w0, w1); c.h[1] = pkf16(w2, w3);
  c.h[2] = pkf16(w4, w5); c.h[3] = pkf16(w6, w7);
  return c.v;
}
// broadcast A-fragment from packed-f16 LDS (16B per lane-group, conflict-free)
__device__ __forceinline__ h8 ldfrag(const uint32_t* p) {
  union { uint4 u; h8 v; } c;
  c.u = *(const uint4*)p;
  return c.v;
}

__device__ __forceinline__ float tanh_fast(float a) {
  float aa = fabsf(a);
  float e  = __expf(2.f * aa);
  float th = 1.f - 2.f * __builtin_amdgcn_rcpf(e + 1.f);
  return copysignf(th, a);
}
__device__ __forceinline__ float softplus_fast(float x) {
  return (x > 20.f) ? x : __logf(1.f + __expf(x));
}

#define MFMA16(A_, B_, C_) __builtin_amdgcn_mfma_f32_16x16x32_f16(A_, B_, C_, 0, 0, 0)

__global__ void __attribute__((amdgpu_flat_work_group_size(NT_, NT_)))
                __attribute__((amdgpu_waves_per_eu(2, 2)))
ltc_scan(
    const float* __restrict__ x,
    const float* __restrict__ Wh0, const float* __restrict__ bh0,
    const float* __restrict__ Wx0, const float* __restrict__ bx0,
    const float* __restrict__ Wt0, const float* __restrict__ bt0,
    const float* __restrict__ tau0, const float* __restrict__ g0,
    const float* __restrict__ be0,
    const float* __restrict__ Wh1, const float* __restrict__ bh1,
    const float* __restrict__ Wx1, const float* __restrict__ bx1,
    const float* __restrict__ Wt1, const float* __restrict__ bt1,
    const float* __restrict__ tau1, const float* __restrict__ g1,
    const float* __restrict__ be1,
    float* __restrict__ out)
{
  __shared__ __align__(16) uint32_t h0p[2][64];   // hc0 packed f16, dbuf
  __shared__ __align__(16) uint32_t h1p[2][64];   // hc1 packed f16, dbuf
  __shared__ __align__(16) uint32_t x4[4][32];    // x[t] packed f16, 4-ring
  __shared__ __align__(16) float    part[4][4];   // {s_L0,s2_L0,s_L1,s2_L1} 4-ring

  const int tid = threadIdx.x;
  const int wid = tid >> 6;
  const int l   = tid & 63;
  const int g4  = (l >> 4) << 2;    // LDS u32 offset of this dup-group's frag
  const int g8  = (l >> 4) << 3;    // k offset (floats) of this dup-group
  const int b   = blockIdx.x;
  const float* xg = x + (size_t)b * (T_ * F_);
  const bool selT1 = (l & 16) != 0; // lanes 16-31 / 48-63 serve tile 1

  if (tid < 128) { ((uint32_t*)h0p)[tid] = 0u; ((uint32_t*)h1p)[tid] = 0u; }
  if (tid < 16)  ((float*)part)[tid] = 0.f;
  if (tid < 32) {                   // stage x[0], x[1]
    float2 a = *(const float2*)(xg + 2 * tid);
    float2 c = *(const float2*)(xg + F_ + 2 * tid);
    x4[0][tid] = as_u32(pkf16(a.x, a.y));
    x4[1][tid] = as_u32(pkf16(c.x, c.y));
  }
  __syncthreads();

  if (wid < 4) {
    // ========== group A: layer 0, step t = i; cols wid*32 .. wid*32+31 ==========
    const int c0 = wid * 32 + (l & 15);      // tile-0 col (weight load)
    const int ct = wid * 32 + (l & 31);      // this lane's tail col
    h8 wh0[4], wh1[4], wx0[2], wx1[2], wt0[2], wt1[2];
    float cg, cb;
    {
      float dg0 = 0.f, db0 = 0.f, dg1 = 0.f, db1 = 0.f;
      const float* p0 = Wh0 + c0 * H_ + g8;
      const float* p1 = Wh0 + (c0 + 16) * H_ + g8;
      #pragma unroll
      for (int m = 0; m < 4; ++m) {
        wh0[m] = packfrag_g(p0 + 32 * m, g0 + g8 + 32 * m, be0 + g8 + 32 * m, dg0, db0);
        wh1[m] = packfrag_g(p1 + 32 * m, g0 + g8 + 32 * m, be0 + g8 + 32 * m, dg1, db1);
      }
      dg0 += __shfl_xor(dg0, 16); dg0 += __shfl_xor(dg0, 32);
      db0 += __shfl_xor(db0, 16); db0 += __shfl_xor(db0, 32);
      dg1 += __shfl_xor(dg1, 16); dg1 += __shfl_xor(dg1, 32);
      db1 += __shfl_xor(db1, 16); db1 += __shfl_xor(db1, 32);
      cg = selT1 ? dg1 : dg0; cb = selT1 ? db1 : db0;
      const float* q0 = Wx0 + c0 * F_ + g8;
      const float* q1 = Wx0 + (c0 + 16) * F_ + g8;
      const float* r0 = Wt0 + c0 * F_ + g8;
      const float* r1 = Wt0 + (c0 + 16) * F_ + g8;
      #pragma unroll
      for (int m = 0; m < 2; ++m) {
        wx0[m] = packfrag(q0 + 32 * m); wx1[m] = packfrag(q1 + 32 * m);
        wt0[m] = packfrag(r0 + 32 * m); wt1[m] = packfrag(r1 + 32 * m);
      }
    }
    const float bhx = bh0[ct] + bx0[ct];
    const float btr = bt0[ct], taub = tau0[ct], gr = g0[ct], ber = be0[ct];
    const int  widx = wid * 16 + ((l & 31) >> 1);
    const bool wlane = ((l & 33) == 0);      // even col, lower 32
    const bool st = (wid == 0) && (l < 32);

    float hcp = 0.f;
    float2 xcur;                     // x[i+2], loaded one phase early
    if (st) xcur = *(const float2*)(xg + 2 * F_ + 2 * l);

    #pragma unroll 4
    for (int i = 0; i <= T_; ++i) {
      const float2 stt = *(const float2*)&part[(i + 3) & 3][0];  // L0 stats of hc0[i-1]
      if (st) {                      // write x[i+2]; issue load of x[i+3]
        x4[(i + 2) & 3][l] = as_u32(pkf16(xcur.x, xcur.y));
        int tn = (i + 3 < T_) ? (i + 3) : (T_ - 1);
        xcur = *(const float2*)(xg + tn * F_ + 2 * l);
      }
      const uint32_t* ub = h0p[(i + 1) & 1];       // hc0[i-1]
      const uint32_t* xb = x4[i & 3];              // x[i]
      f32x4 aH0 = {0.f,0.f,0.f,0.f}, aH1 = {0.f,0.f,0.f,0.f};
      f32x4 aX0 = {0.f,0.f,0.f,0.f}, aX1 = {0.f,0.f,0.f,0.f};
      f32x4 aT0 = {0.f,0.f,0.f,0.f}, aT1 = {0.f,0.f,0.f,0.f};
      #pragma unroll
      for (int m = 0; m < 4; ++m) {
        h8 af = ldfrag(ub + m * 16 + g4);          // shared by both tiles
        aH0 = MFMA16(af, wh0[m], aH0);
        aH1 = MFMA16(af, wh1[m], aH1);
      }
      #pragma unroll
      for (int m = 0; m < 2; ++m) {
        h8 xf = ldfrag(xb + m * 16 + g4);
        aX0 = MFMA16(xf, wx0[m], aX0);
        aX1 = MFMA16(xf, wx1[m], aX1);
        aT0 = MFMA16(xf, wt0[m], aT0);
        aT1 = MFMA16(xf, wt1[m], aT1);
      }
      float aH = selT1 ? aH1[0] : aH0[0];
      float aX = selT1 ? aX1[0] : aX0[0];
      float aT = selT1 ? aT1[0] : aT0[0];
      float mu = stt.x * (1.f / 128.f);
      float m2 = stt.y * (1.f / 128.f);
      float rstd = rsq_fast(m2 - mu * mu + EPS_);
      float fl = (i > 0) ? 1.f : 0.f;
      float sc = fl * rstd;
      float pa = fmaf(sc, aH, fmaf(-sc * mu, cg, fl * cb)) + aX + bhx;
      float pt = aT + btr;
      float f   = tanh_fast(pa);
      float tau = taub + softplus_fast(pt);
      float hold = fl * fmaf((hcp - mu) * rstd, gr, ber);   // hn0[i-1][ct]
      float hc  = fmaf(f - hold, __builtin_amdgcn_rcpf(tau), hold);
      float hc2 = __shfl_xor(hc, 1);
      if (wlane) h0p[i & 1][widx] = as_u32(pkf16(hc, hc2));
      float v = (l & 32) ? hc * hc : hc;           // dup rows carry s2
      v = red16(v); v += __shfl_xor(v, 16);
      if (l == 0)  atomicAdd(&part[i & 3][0], v);  // Sum hc
      if (l == 32) atomicAdd(&part[i & 3][1], v);  // Sum hc^2
      hcp = hc;
      __syncthreads();                             // the ONE barrier per phase
    }
  } else {
    // ========== group B: layer 1, step t = i-1; cols (wid-4)*32 .. +31 ==========
    const int c0 = (wid - 4) * 32 + (l & 15);
    const int ct = (wid - 4) * 32 + (l & 31);
    h8 vh0[4], vh1[4], vx0[4], vx1[4], vt0[4], vt1[4];
    float cAg, cAb, cBg, cBb, cTg, cTb;
    {
      float d1=0.f,d2=0.f,d3=0.f,d4=0.f,d5=0.f,d6=0.f;   // tile 0
      float e1=0.f,e2=0.f,e3=0.f,e4=0.f,e5=0.f,e6=0.f;   // tile 1
      const float* p0 = Wh1 + c0 * H_ + g8;
      const float* p1 = Wh1 + (c0 + 16) * H_ + g8;
      const float* q0 = Wx1 + c0 * H_ + g8;
      const float* q1 = Wx1 + (c0 + 16) * H_ + g8;
      const float* r0 = Wt1 + c0 * H_ + g8;
      const float* r1 = Wt1 + (c0 + 16) * H_ + g8;
      #pragma unroll
      for (int m = 0; m < 4; ++m) {
        vh0[m] = packfrag_g(p0 + 32 * m, g1 + g8 + 32 * m, be1 + g8 + 32 * m, d1, d2);
        vh1[m] = packfrag_g(p1 + 32 * m, g1 + g8 + 32 * m, be1 + g8 + 32 * m, e1, e2);
        vx0[m] = packfrag_g(q0 + 32 * m, g0 + g8 + 32 * m, be0 + g8 + 32 * m, d3, d4);
        vx1[m] = packfrag_g(q1 + 32 * m, g0 + g8 + 32 * m, be0 + g8 + 32 * m, e3, e4);
        vt0[m] = packfrag_g(r0 + 32 * m, g0 + g8 + 32 * m, be0 + g8 + 32 * m, d5, d6);
        vt1[m] = packfrag_g(r1 + 32 * m, g0 + g8 + 32 * m, be0 + g8 + 32 * m, e5, e6);
      }
      d1 += __shfl_xor(d1, 16); d1 += __shfl_xor(d1, 32);
      d2 += __shfl_xor(d2, 16); d2 += __shfl_xor(d2, 32);
      d3 += __shfl_xor(d3, 16); d3 += __shfl_xor(d3, 32);
      d4 += __shfl_xor(d4, 16); d4 += __shfl_xor(d4, 32);
      d5 += __shfl_xor(d5, 16); d5 += __shfl_xor(d5, 32);
      d6 += __shfl_xor(d6, 16); d6 += __shfl_xor(d6, 32);
      e1 += __shfl_xor(e1, 16); e1 += __shfl_xor(e1, 32);
      e2 += __shfl_xor(e2, 16); e2 += __shfl_xor(e2, 32);
      e3 += __shfl_xor(e3, 16); e3 += __shfl_xor(e3, 32);
      e4 += __shfl_xor(e4, 16); e4 += __shfl_xor(e4, 32);
      e5 += __shfl_xor(e5, 16); e5 += __shfl_xor(e5, 32);
      e6 += __shfl_xor(e6, 16); e6 += __shfl_xor(e6, 32);
      cAg = selT1 ? e1 : d1; cAb = selT1 ? e2 : d2;
      cBg = selT1 ? e3 : d3; cBb = selT1 ? e4 : d4;
      cTg = selT1 ? e5 : d5; cTb = selT1 ? e6 : d6;
    }
    const float bhx = bh1[ct] + bx1[ct];
    const float btr = bt1[ct], taub = tau1[ct], gr = g1[ct], ber = be1[ct];
    const int  widx = (wid - 4) * 16 + ((l & 31) >> 1);
    const bool wlane = ((l & 33) == 0);
    const bool zt = (tid == NT_ - 1);              // ring zero-er

    float hcp = 0.f;
    #pragma unroll 2
    for (int i = 0; i <= T_; ++i) {
      const float4 P = *(const float4*)&part[(i + 3) & 3][0];  // both layers' stats
      if (zt) *(float4*)&part[(i + 2) & 3][0] = make_float4(0.f, 0.f, 0.f, 0.f);
      const uint32_t* u1b = h1p[(i + 1) & 1];      // hc1[i-2]
      const uint32_t* u0b = h0p[(i + 1) & 1];      // hc0[i-1]
      f32x4 aA0 = {0.f,0.f,0.f,0.f}, aA1 = {0.f,0.f,0.f,0.f};
      f32x4 aB0 = {0.f,0.f,0.f,0.f}, aB1 = {0.f,0.f,0.f,0.f};
      f32x4 aT0 = {0.f,0.f,0.f,0.f}, aT1 = {0.f,0.f,0.f,0.f};
      #pragma unroll
      for (int m = 0; m < 4; ++m) {
        h8 af = ldfrag(u1b + m * 16 + g4);         // shared by both tiles
        aA0 = MFMA16(af, vh0[m], aA0);
        aA1 = MFMA16(af, vh1[m], aA1);
      }
      #pragma unroll
      for (int m = 0; m < 4; ++m) {
        h8 f0 = ldfrag(u0b + m * 16 + g4);
        aB0 = MFMA16(f0, vx0[m], aB0);
        aB1 = MFMA16(f0, vx1[m], aB1);
        aT0 = MFMA16(f0, vt0[m], aT0);
        aT1 = MFMA16(f0, vt1[m], aT1);
      }
      float aA = selT1 ? aA1[0] : aA0[0];
      float aB = selT1 ? aB1[0] : aB0[0];
      float aT = selT1 ? aT1[0] : aT0[0];
      float mu0 = P.x * (1.f / 128.f), m20 = P.y * (1.f / 128.f);
      float mu1 = P.z * (1.f / 128.f), m21 = P.w * (1.f / 128.f);
      float rstd0 = rsq_fast(m20 - mu0 * mu0 + EPS_);
      float rstd1 = rsq_fast(m21 - mu1 * mu1 + EPS_);
      float fl0 = (i > 0) ? 1.f : 0.f;
      float fl1 = (i > 1) ? 1.f : 0.f;
      float sc0 = fl0 * rstd0, sc1 = fl1 * rstd1;
      float pa = fmaf(sc1, aA, fmaf(-sc1 * mu1, cAg, fl1 * cAb))
               + fmaf(sc0, aB, fmaf(-sc0 * mu0, cBg, fl0 * cBb)) + bhx;
      float pt = fmaf(sc0, aT, fmaf(-sc0 * mu0, cTg, fl0 * cTb)) + btr;
      float f   = tanh_fast(pa);
      float tau = taub + softplus_fast(pt);
      float hold = fl1 * fmaf((hcp - mu1) * rstd1, gr, ber);  // hn1[i-2][ct]
      float hc  = fmaf(f - hold, __builtin_amdgcn_rcpf(tau), hold);
      float hc2 = __shfl_xor(hc, 1);
      bool we = (i > 0);
      if (we && wlane) h1p[i & 1][widx] = as_u32(pkf16(hc, hc2));
      float v = (l & 32) ? hc * hc : hc;
      v = red16(v); v += __shfl_xor(v, 16);
      if (we && l == 0)  atomicAdd(&part[i & 3][2], v);
      if (we && l == 32) atomicAdd(&part[i & 3][3], v);
      if (we) hcp = hc;
      __syncthreads();                             // the ONE barrier per phase
    }
    // epilogue: hn1[T-1] from stats published at phase T_ (slot T_&3 = 0)
    {
      float mu1 = part[T_ & 3][2] * (1.f / 128.f);
      float m21 = part[T_ & 3][3] * (1.f / 128.f);
      float rstd1 = rsq_fast(m21 - mu1 * mu1 + EPS_);
      float hn = fmaf((hcp - mu1) * rstd1, gr, ber);
      if (l < 32) out[b * H_ + ct] = hn;
    }
  }
}

extern "C" void kernel_launch(void* const* d_in, const int* in_sizes, int n_in,
                              void* d_out, int out_size, void* d_ws, size_t ws_size,
                              hipStream_t stream) {
  const float* x    = (const float*)d_in[0];
  const float* Wh0  = (const float*)d_in[1];
  const float* bh0  = (const float*)d_in[2];
  const float* Wx0  = (const float*)d_in[3];
  const float* bx0  = (const float*)d_in[4];
  const float* Wt0  = (const float*)d_in[5];
  const float* bt0  = (const float*)d_in[6];
  const float* tau0 = (const float*)d_in[7];
  const float* g0   = (const float*)d_in[8];
  const float* be0  = (const float*)d_in[9];
  const float* Wh1  = (const float*)d_in[10];
  const float* bh1  = (const float*)d_in[11];
  const float* Wx1  = (const float*)d_in[12];
  const float* bx1  = (const float*)d_in[13];
  const float* Wt1  = (const float*)d_in[14];
  const float* bt1  = (const float*)d_in[15];
  const float* tau1 = (const float*)d_in[16];
  const float* g1   = (const float*)d_in[17];
  const float* be1  = (const float*)d_in[18];
  float* out        = (float*)d_out;

  ltc_scan<<<B_, NT_, 0, stream>>>(x, Wh0, bh0, Wx0, bx0, Wt0, bt0, tau0, g0, be0,
                                   Wh1, bh1, Wx1, bx1, Wt1, bt1, tau1, g1, be1, out);
}